// Round 16
// baseline (1643.713 us; speedup 1.0000x reference)
//
#include <hip/hip_runtime.h>

#define K_DIM 256
__device__ __forceinline__ float lrelu_f(float x) { return x >= 0.f ? x : 0.2f * x; }

// ---------------- graph prep kernels ----------------

__global__ __launch_bounds__(256) void hist_kernel(const int* __restrict__ dst,
                                                   int* __restrict__ cnt, int E) {
  int e = blockIdx.x * 256 + threadIdx.x;
  if (e < E) atomicAdd(&cnt[dst[e]], 1);
}

__global__ __launch_bounds__(256) void dinv_kernel(const int* __restrict__ cnt,
                                                   float* __restrict__ dinv, int n) {
  int i = blockIdx.x * 256 + threadIdx.x;
  if (i < n) dinv[i] = rsqrtf((float)cnt[i] + 1.0f);
}

__global__ __launch_bounds__(256) void scan1_kernel(const int* __restrict__ cnt,
                                                    int* __restrict__ incl,
                                                    int* __restrict__ bsum, int n) {
  __shared__ int sm[256];
  int t = threadIdx.x;
  int i = blockIdx.x * 256 + t;
  int v = (i < n) ? cnt[i] : 0;
  sm[t] = v;
  __syncthreads();
  for (int off = 1; off < 256; off <<= 1) {
    int u = (t >= off) ? sm[t - off] : 0;
    __syncthreads();
    sm[t] += u;
    __syncthreads();
  }
  if (i < n) incl[i] = sm[t];
  if (t == 255) bsum[blockIdx.x] = sm[255];
}

__global__ __launch_bounds__(256) void scan2_kernel(const int* __restrict__ bsum,
                                                    int* __restrict__ boff, int nb) {
  __shared__ int sm[256];
  int t = threadIdx.x;
  int v = (t < nb) ? bsum[t] : 0;
  sm[t] = v;
  __syncthreads();
  for (int off = 1; off < 256; off <<= 1) {
    int u = (t >= off) ? sm[t - off] : 0;
    __syncthreads();
    sm[t] += u;
    __syncthreads();
  }
  boff[t] = sm[t] - v;  // exclusive
}

__global__ __launch_bounds__(256) void scan3_kernel(const int* __restrict__ incl,
                                                    const int* __restrict__ boff,
                                                    int* __restrict__ rowptr, int n) {
  int i = blockIdx.x * 256 + threadIdx.x;
  if (i < n) rowptr[i + 1] = incl[i] + boff[blockIdx.x];
  if (i == 0) rowptr[0] = 0;
}

__global__ __launch_bounds__(256) void scatter_kernel(const int* __restrict__ src,
                                                      const int* __restrict__ dst,
                                                      const int* __restrict__ rowptr,
                                                      int* __restrict__ cursor,
                                                      const float* __restrict__ dinv,
                                                      int* __restrict__ esrc,
                                                      float* __restrict__ ew, int E) {
  int e = blockIdx.x * 256 + threadIdx.x;
  if (e < E) {
    int d = dst[e];
    int p = rowptr[d] + atomicAdd(&cursor[d], 1);
    int s = src[e];
    esrc[p] = s;
    ew[p] = dinv[s];
  }
}

// ---------------- GEMM (R8: best known, ~100us/dispatch, 52% of fp32 peak) ----------------
// 128x128 tile, 256 threads, 8x8 microtile, BK=32, PAD=132 (2-way staging conflict).
// R9 LESSON: bigger microtile (16x8, 128thr) -> 6 waves/CU -> latency-bound, SLOWER.
// R6 LESSON: dbuf+prefetch -> VGPR 184 -> 9% occ -> 2x slower. Keep single-buffer.

template <bool LRELU, int NCOLS>
__global__ __launch_bounds__(256) void gemm_kernel(const float* __restrict__ A,
                                                   const float* __restrict__ W,
                                                   float* __restrict__ H, int M) {
  constexpr int BK = 32;
  constexpr int PAD = 132;
  __shared__ float As[BK][PAD];
  __shared__ float Ws[BK][PAD];
  const int bm = blockIdx.x * 128;
  const int bn = blockIdx.y * 128;
  const int tid = threadIdx.x;
  const int tx = tid & 15;
  const int ty = tid >> 4;
  const int lr = tid >> 2;
  const int lk = (tid & 3) << 2;

  float acc[2][2][4][4];
#pragma unroll
  for (int a = 0; a < 2; a++)
#pragma unroll
    for (int b = 0; b < 2; b++)
#pragma unroll
      for (int i = 0; i < 4; i++)
#pragma unroll
        for (int j = 0; j < 4; j++) acc[a][b][i][j] = 0.f;

  for (int k0 = 0; k0 < K_DIM; k0 += BK) {
#pragma unroll
    for (int kh = 0; kh < 2; ++kh) {
      const int ks = kh * 16 + lk;
#pragma unroll
      for (int h = 0; h < 2; ++h) {
        int row = bm + h * 64 + lr;
        int rc = row < M ? row : M - 1;
        float4 v = *(const float4*)(A + (size_t)rc * K_DIM + k0 + ks);
        if (LRELU) {
          v.x = lrelu_f(v.x); v.y = lrelu_f(v.y); v.z = lrelu_f(v.z); v.w = lrelu_f(v.w);
        }
        As[ks + 0][h * 64 + lr] = v.x;
        As[ks + 1][h * 64 + lr] = v.y;
        As[ks + 2][h * 64 + lr] = v.z;
        As[ks + 3][h * 64 + lr] = v.w;
      }
#pragma unroll
      for (int h = 0; h < 2; ++h) {
        int row = bn + h * 64 + lr;
        float4 v = *(const float4*)(W + (size_t)row * K_DIM + k0 + ks);
        Ws[ks + 0][h * 64 + lr] = v.x;
        Ws[ks + 1][h * 64 + lr] = v.y;
        Ws[ks + 2][h * 64 + lr] = v.z;
        Ws[ks + 3][h * 64 + lr] = v.w;
      }
    }
    __syncthreads();
#pragma unroll 8
    for (int kk = 0; kk < BK; ++kk) {
      float4 va0 = *(const float4*)&As[kk][ty * 4];
      float4 va1 = *(const float4*)&As[kk][64 + ty * 4];
      float4 vb0 = *(const float4*)&Ws[kk][tx * 4];
      float4 vb1 = *(const float4*)&Ws[kk][64 + tx * 4];
      float a0[4] = {va0.x, va0.y, va0.z, va0.w};
      float a1[4] = {va1.x, va1.y, va1.z, va1.w};
      float b0[4] = {vb0.x, vb0.y, vb0.z, vb0.w};
      float b1[4] = {vb1.x, vb1.y, vb1.z, vb1.w};
#pragma unroll
      for (int i = 0; i < 4; i++)
#pragma unroll
        for (int j = 0; j < 4; j++) {
          acc[0][0][i][j] = fmaf(a0[i], b0[j], acc[0][0][i][j]);
          acc[0][1][i][j] = fmaf(a0[i], b1[j], acc[0][1][i][j]);
          acc[1][0][i][j] = fmaf(a1[i], b0[j], acc[1][0][i][j]);
          acc[1][1][i][j] = fmaf(a1[i], b1[j], acc[1][1][i][j]);
        }
    }
    __syncthreads();
  }

#pragma unroll
  for (int mh = 0; mh < 2; ++mh)
#pragma unroll
    for (int i = 0; i < 4; i++) {
      int row = bm + mh * 64 + ty * 4 + i;
      if (row < M) {
#pragma unroll
        for (int nh = 0; nh < 2; ++nh) {
          float4 o;
          o.x = acc[mh][nh][i][0];
          o.y = acc[mh][nh][i][1];
          o.z = acc[mh][nh][i][2];
          o.w = acc[mh][nh][i][3];
          *(float4*)(H + (size_t)row * NCOLS + bn + nh * 64 + tx * 4) = o;
        }
      }
    }
}

// ---------------- column-sliced aggregation, L2-resident 16-col slices ----------------
// out[i] = dinv_i*(sum_e dinv_s*h_s) + dinv_i^2*h_i + b
// R14: CW=16 cols per XCD group -> per-XCD working set 50k*16*4 = 3.2MB < 4MB L2.
// COLS=256 runs as TWO sequential dispatches (colbase 0, 128) so the two halves
// never co-thrash an XCD's L2. g = blockIdx.x & 7 rides round-robin XCD dispatch.
// LINEAR node order (R12: sorted order scattered coalesced self/write traffic).
// 8-deep edge batch pipeline kept from R13 (neutral at L3 latency, should help at
// L2-hit latency). Summation order per node unchanged -> bit-identical.

template <int COLS>
__global__ __launch_bounds__(256) void aggregate_kernel(
    const float* __restrict__ H, const int* __restrict__ rowptr,
    const int* __restrict__ esrc, const float* __restrict__ ew,
    const float* __restrict__ dinv, const float* __restrict__ bias,
    float* __restrict__ out, int n, int colbase) {
  constexpr int CW = 16;       // cols per group (L2-fit: 3.2MB/XCD)
  constexpr int TPN = CW / 4;  // 4 threads per node
  constexpr int NPB = 256 / TPN;  // 64 nodes per block
  const int g = blockIdx.x & 7;
  const int nb = blockIdx.x >> 3;
  const int t = threadIdx.x;
  const int ln = t / TPN;
  const int ct = t % TPN;
  const int node = nb * NPB + ln;
  if (node >= n) return;
  const int c0 = colbase + g * CW + ct * 4;
  const float* __restrict__ Hc = H + c0;
  const float di = dinv[node];

  float4 hs = *(const float4*)(Hc + (size_t)node * COLS);
  float a0 = di * hs.x, a1 = di * hs.y, a2 = di * hs.z, a3 = di * hs.w;

  const int e0 = rowptr[node];
  const int e1 = rowptr[node + 1];
  int e = e0;
  const int m8 = e0 + ((e1 - e0) & ~7);

  if (e < m8) {
    int s[8];
    float w[8];
#pragma unroll
    for (int j = 0; j < 8; ++j) { s[j] = esrc[e + j]; w[j] = ew[e + j]; }
    e += 8;
    for (; e < m8; e += 8) {
      int s2[8];
      float w2[8];
#pragma unroll
      for (int j = 0; j < 8; ++j) { s2[j] = esrc[e + j]; w2[j] = ew[e + j]; }
#pragma unroll
      for (int j = 0; j < 8; ++j) {
        float4 h = *(const float4*)(Hc + (size_t)s[j] * COLS);
        a0 = fmaf(w[j], h.x, a0);
        a1 = fmaf(w[j], h.y, a1);
        a2 = fmaf(w[j], h.z, a2);
        a3 = fmaf(w[j], h.w, a3);
      }
#pragma unroll
      for (int j = 0; j < 8; ++j) { s[j] = s2[j]; w[j] = w2[j]; }
    }
#pragma unroll
    for (int j = 0; j < 8; ++j) {
      float4 h = *(const float4*)(Hc + (size_t)s[j] * COLS);
      a0 = fmaf(w[j], h.x, a0);
      a1 = fmaf(w[j], h.y, a1);
      a2 = fmaf(w[j], h.z, a2);
      a3 = fmaf(w[j], h.w, a3);
    }
  }
  for (; e < e1; ++e) {
    int s = esrc[e];
    float w = ew[e];
    float4 h = *(const float4*)(Hc + (size_t)s * COLS);
    a0 = fmaf(w, h.x, a0);
    a1 = fmaf(w, h.y, a1);
    a2 = fmaf(w, h.z, a2);
    a3 = fmaf(w, h.w, a3);
  }

  float4 b = *(const float4*)(bias + c0);
  float4 o;
  o.x = fmaf(di, a0, b.x);
  o.y = fmaf(di, a1, b.y);
  o.z = fmaf(di, a2, b.z);
  o.w = fmaf(di, a3, b.w);
  *(float4*)(out + (size_t)node * COLS + c0) = o;
}

// ---------------- launch ----------------

extern "C" void kernel_launch(void* const* d_in, const int* in_sizes, int n_in,
                              void* d_out, int out_size, void* d_ws, size_t ws_size,
                              hipStream_t stream) {
  (void)n_in; (void)out_size; (void)ws_size;
  const float* x = (const float*)d_in[0];
  const int N = in_sizes[0] / 256;
  const int* ei = (const int*)d_in[1];
  const int E = in_sizes[1] / 2;
  const int* srcp = ei;
  const int* dstp = ei + E;
  const float* Wl[6];
  const float* Bl[6];
  for (int i = 0; i < 6; i++) {
    Wl[i] = (const float*)d_in[2 + 2 * i];
    Bl[i] = (const float*)d_in[3 + 2 * i];
  }
  float* out = (float*)d_out;

  char* p = (char*)d_ws;
  auto carve = [&](size_t bytes) {
    char* r = p;
    p += (bytes + 255) & ~(size_t)255;
    return (void*)r;
  };
  float* bufA = (float*)carve((size_t)N * 256 * 4);
  float* bufB = (float*)carve((size_t)N * 256 * 4);
  int* cnt = (int*)carve((size_t)N * 4);
  float* dinv = (float*)carve((size_t)N * 4);
  int* incl = (int*)carve((size_t)N * 4);
  int* rowptr = (int*)carve((size_t)(N + 1) * 4);
  int* esrc = (int*)carve((size_t)E * 4);
  float* ew = (float*)carve((size_t)E * 4);
  int* bsum = (int*)carve(1024);
  int* boff = (int*)carve(1024);

  const int NB = (N + 255) / 256;

  hipMemsetAsync(cnt, 0, (size_t)N * 4, stream);
  hist_kernel<<<(E + 255) / 256, 256, 0, stream>>>(dstp, cnt, E);
  dinv_kernel<<<NB, 256, 0, stream>>>(cnt, dinv, N);
  scan1_kernel<<<NB, 256, 0, stream>>>(cnt, incl, bsum, N);
  scan2_kernel<<<1, 256, 0, stream>>>(bsum, boff, NB);
  scan3_kernel<<<NB, 256, 0, stream>>>(incl, boff, rowptr, N);
  hipMemsetAsync(cnt, 0, (size_t)N * 4, stream);
  scatter_kernel<<<(E + 255) / 256, 256, 0, stream>>>(srcp, dstp, rowptr, cnt, dinv,
                                                      esrc, ew, E);

  const int gm = (N + 127) / 128;
  const int gagg = 8 * ((N + 63) / 64);  // 8 groups x node blocks (CW=16)

  // layer 1 (no lrelu on input)
  gemm_kernel<false, 256><<<dim3(gm, 2), 256, 0, stream>>>(x, Wl[0], bufB, N);
  aggregate_kernel<256><<<gagg, 256, 0, stream>>>(bufB, rowptr, esrc, ew, dinv, Bl[0], bufA, N, 0);
  aggregate_kernel<256><<<gagg, 256, 0, stream>>>(bufB, rowptr, esrc, ew, dinv, Bl[0], bufA, N, 128);
  // layers 2..5
  for (int l = 1; l < 5; ++l) {
    gemm_kernel<true, 256><<<dim3(gm, 2), 256, 0, stream>>>(bufA, Wl[l], bufB, N);
    aggregate_kernel<256><<<gagg, 256, 0, stream>>>(bufB, rowptr, esrc, ew, dinv, Bl[l], bufA, N, 0);
    aggregate_kernel<256><<<gagg, 256, 0, stream>>>(bufB, rowptr, esrc, ew, dinv, Bl[l], bufA, N, 128);
  }
  // layer 6 (out dim 128) -> d_out (single pass: CW=16 slice already L2-fit)
  gemm_kernel<true, 128><<<dim3(gm, 1), 256, 0, stream>>>(bufA, Wl[5], bufB, N);
  aggregate_kernel<128><<<gagg, 256, 0, stream>>>(bufB, rowptr, esrc, ew, dinv, Bl[5], out, N, 0);
}

// Round 17
// 1157.430 us; speedup vs baseline: 1.4201x; 1.4201x over previous
//
#include <hip/hip_runtime.h>
#include <hip/hip_bf16.h>

#define K_DIM 256
__device__ __forceinline__ float lrelu_f(float x) { return x >= 0.f ? x : 0.2f * x; }

using bf16x8 = __attribute__((ext_vector_type(8))) short;
using f32x4 = __attribute__((ext_vector_type(4))) float;

__device__ __forceinline__ unsigned short f2bf(float x) {
  __hip_bfloat16 b = __float2bfloat16(x);
  return *(unsigned short*)&b;
}
__device__ __forceinline__ float bf2f(unsigned short u) {
  __hip_bfloat16 b = *(__hip_bfloat16*)&u;
  return __bfloat162float(b);
}

// ---------------- graph prep kernels ----------------

__global__ __launch_bounds__(256) void hist_kernel(const int* __restrict__ dst,
                                                   int* __restrict__ cnt, int E) {
  int e = blockIdx.x * 256 + threadIdx.x;
  if (e < E) atomicAdd(&cnt[dst[e]], 1);
}

__global__ __launch_bounds__(256) void dinv_kernel(const int* __restrict__ cnt,
                                                   float* __restrict__ dinv, int n) {
  int i = blockIdx.x * 256 + threadIdx.x;
  if (i < n) dinv[i] = rsqrtf((float)cnt[i] + 1.0f);
}

__global__ __launch_bounds__(256) void scan1_kernel(const int* __restrict__ cnt,
                                                    int* __restrict__ incl,
                                                    int* __restrict__ bsum, int n) {
  __shared__ int sm[256];
  int t = threadIdx.x;
  int i = blockIdx.x * 256 + t;
  int v = (i < n) ? cnt[i] : 0;
  sm[t] = v;
  __syncthreads();
  for (int off = 1; off < 256; off <<= 1) {
    int u = (t >= off) ? sm[t - off] : 0;
    __syncthreads();
    sm[t] += u;
    __syncthreads();
  }
  if (i < n) incl[i] = sm[t];
  if (t == 255) bsum[blockIdx.x] = sm[255];
}

__global__ __launch_bounds__(256) void scan2_kernel(const int* __restrict__ bsum,
                                                    int* __restrict__ boff, int nb) {
  __shared__ int sm[256];
  int t = threadIdx.x;
  int v = (t < nb) ? bsum[t] : 0;
  sm[t] = v;
  __syncthreads();
  for (int off = 1; off < 256; off <<= 1) {
    int u = (t >= off) ? sm[t - off] : 0;
    __syncthreads();
    sm[t] += u;
    __syncthreads();
  }
  boff[t] = sm[t] - v;  // exclusive
}

__global__ __launch_bounds__(256) void scan3_kernel(const int* __restrict__ incl,
                                                    const int* __restrict__ boff,
                                                    int* __restrict__ rowptr, int n) {
  int i = blockIdx.x * 256 + threadIdx.x;
  if (i < n) rowptr[i + 1] = incl[i] + boff[blockIdx.x];
  if (i == 0) rowptr[0] = 0;
}

__global__ __launch_bounds__(256) void scatter_kernel(const int* __restrict__ src,
                                                      const int* __restrict__ dst,
                                                      const int* __restrict__ rowptr,
                                                      int* __restrict__ cursor,
                                                      const float* __restrict__ dinv,
                                                      int* __restrict__ esrc,
                                                      float* __restrict__ ew, int E) {
  int e = blockIdx.x * 256 + threadIdx.x;
  if (e < E) {
    int d = dst[e];
    int p = rowptr[d] + atomicAdd(&cursor[d], 1);
    int s = src[e];
    esrc[p] = s;
    ew[p] = dinv[s];
  }
}

// ---------------- split: y=(lrelu)(in); hi=bf16(y); lo=bf16(y-hi) ----------------

template <bool LRELU>
__global__ __launch_bounds__(256) void split_kernel(const float* __restrict__ in,
                                                    unsigned short* __restrict__ hi,
                                                    unsigned short* __restrict__ lo,
                                                    int n4) {
  int i = blockIdx.x * 256 + threadIdx.x;
  if (i >= n4) return;
  float4 v = *(const float4*)(in + (size_t)i * 4);
  if (LRELU) {
    v.x = lrelu_f(v.x); v.y = lrelu_f(v.y); v.z = lrelu_f(v.z); v.w = lrelu_f(v.w);
  }
  ushort4 h, l;
  h.x = f2bf(v.x); l.x = f2bf(v.x - bf2f(h.x));
  h.y = f2bf(v.y); l.y = f2bf(v.y - bf2f(h.y));
  h.z = f2bf(v.z); l.z = f2bf(v.z - bf2f(h.z));
  h.w = f2bf(v.w); l.w = f2bf(v.w - bf2f(h.w));
  *(ushort4*)(hi + (size_t)i * 4) = h;
  *(ushort4*)(lo + (size_t)i * 4) = l;
}

// ---------------- MFMA GEMM: H[M,NCOLS] = (Ah+Al)[M,256] @ (Wh+Wl)[NCOLS,256]^T ----------------
// Split-bf16 3-term: Ah*Wh + Ah*Wl + Al*Wh (Al*Wl dropped, ~2^-18 rel).
// Block 256thr = 4 waves; block tile 256(M) x 64(N); wave tile 64x64 = 4x4 of 16x16.
// No LDS: per k-step each lane loads 16B frags direct from global (L2-served).
// mfma_f32_16x16x32_bf16: A-frag lane l -> row l&15, k-chunk (l>>4)*8 (same map
// used for BOTH operands -> any k-permutation cancels in the dot product).
// C/D layout (m89-verified): col=lane&15, row=(lane>>4)*4+reg.

template <int NCOLS>
__global__ __launch_bounds__(256) void mfma_gemm_kernel(
    const unsigned short* __restrict__ Ah, const unsigned short* __restrict__ Al,
    const unsigned short* __restrict__ Wh, const unsigned short* __restrict__ Wl,
    float* __restrict__ H, int M) {
  const int tid = threadIdx.x;
  const int wv = tid >> 6;
  const int lane = tid & 63;
  const int r = lane & 15;
  const int g = lane >> 4;
  const int bm = blockIdx.x * 256 + wv * 64;
  const int bn = blockIdx.y * 64;

  f32x4 acc[4][4];
#pragma unroll
  for (int i = 0; i < 4; ++i)
#pragma unroll
    for (int t = 0; t < 4; ++t) acc[i][t] = {0.f, 0.f, 0.f, 0.f};

  size_t aoff[4];
#pragma unroll
  for (int i = 0; i < 4; ++i) {
    int row = bm + i * 16 + r;
    if (row >= M) row = M - 1;
    aoff[i] = (size_t)row * K_DIM;
  }
  size_t woff[4];
#pragma unroll
  for (int t = 0; t < 4; ++t) woff[t] = (size_t)(bn + t * 16 + r) * K_DIM;

  for (int k0 = 0; k0 < K_DIM; k0 += 32) {
    const int kb = k0 + g * 8;
    bf16x8 ah[4], al[4], bh[4], bl[4];
#pragma unroll
    for (int i = 0; i < 4; ++i) {
      ah[i] = *(const bf16x8*)(Ah + aoff[i] + kb);
      al[i] = *(const bf16x8*)(Al + aoff[i] + kb);
    }
#pragma unroll
    for (int t = 0; t < 4; ++t) {
      bh[t] = *(const bf16x8*)(Wh + woff[t] + kb);
      bl[t] = *(const bf16x8*)(Wl + woff[t] + kb);
    }
#pragma unroll
    for (int i = 0; i < 4; ++i)
#pragma unroll
      for (int t = 0; t < 4; ++t) {
        acc[i][t] = __builtin_amdgcn_mfma_f32_16x16x32_bf16(ah[i], bh[t], acc[i][t], 0, 0, 0);
        acc[i][t] = __builtin_amdgcn_mfma_f32_16x16x32_bf16(ah[i], bl[t], acc[i][t], 0, 0, 0);
        acc[i][t] = __builtin_amdgcn_mfma_f32_16x16x32_bf16(al[i], bh[t], acc[i][t], 0, 0, 0);
      }
  }

#pragma unroll
  for (int i = 0; i < 4; ++i)
#pragma unroll
    for (int t = 0; t < 4; ++t) {
#pragma unroll
      for (int j = 0; j < 4; ++j) {
        int row = bm + i * 16 + g * 4 + j;
        if (row < M) H[(size_t)row * NCOLS + bn + t * 16 + r] = acc[i][t][j];
      }
    }
}

// ---------------- column-sliced aggregation (R13 config: best known, ~90us) ----------------
// out[i] = dinv_i*(sum_e dinv_s*h_s) + dinv_i^2*h_i + b
// CW=COLS/8 col-group per XCD (R7 win). LINEAR node order (R12: sort hurt).
// 8-deep edge index pipeline (R13). R16 LESSON: dispatch time is invariant to
// payload bytes / L2 residency -> bound by edge iteration; this is the floor.

template <int COLS>
__global__ __launch_bounds__(256) void aggregate_kernel(
    const float* __restrict__ H, const int* __restrict__ rowptr,
    const int* __restrict__ esrc, const float* __restrict__ ew,
    const float* __restrict__ dinv, const float* __restrict__ bias,
    float* __restrict__ out, int n) {
  constexpr int CW = COLS / 8;
  constexpr int TPN = CW / 4;
  constexpr int NPB = 256 / TPN;
  const int g = blockIdx.x & 7;
  const int nb = blockIdx.x >> 3;
  const int t = threadIdx.x;
  const int ln = t / TPN;
  const int ct = t % TPN;
  const int node = nb * NPB + ln;
  if (node >= n) return;
  const int c0 = g * CW + ct * 4;
  const float* __restrict__ Hc = H + c0;
  const float di = dinv[node];

  float4 hs = *(const float4*)(Hc + (size_t)node * COLS);
  float a0 = di * hs.x, a1 = di * hs.y, a2 = di * hs.z, a3 = di * hs.w;

  const int e0 = rowptr[node];
  const int e1 = rowptr[node + 1];
  int e = e0;
  const int m8 = e0 + ((e1 - e0) & ~7);

  if (e < m8) {
    int s[8];
    float w[8];
#pragma unroll
    for (int j = 0; j < 8; ++j) { s[j] = esrc[e + j]; w[j] = ew[e + j]; }
    e += 8;
    for (; e < m8; e += 8) {
      int s2[8];
      float w2[8];
#pragma unroll
      for (int j = 0; j < 8; ++j) { s2[j] = esrc[e + j]; w2[j] = ew[e + j]; }
#pragma unroll
      for (int j = 0; j < 8; ++j) {
        float4 h = *(const float4*)(Hc + (size_t)s[j] * COLS);
        a0 = fmaf(w[j], h.x, a0);
        a1 = fmaf(w[j], h.y, a1);
        a2 = fmaf(w[j], h.z, a2);
        a3 = fmaf(w[j], h.w, a3);
      }
#pragma unroll
      for (int j = 0; j < 8; ++j) { s[j] = s2[j]; w[j] = w2[j]; }
    }
#pragma unroll
    for (int j = 0; j < 8; ++j) {
      float4 h = *(const float4*)(Hc + (size_t)s[j] * COLS);
      a0 = fmaf(w[j], h.x, a0);
      a1 = fmaf(w[j], h.y, a1);
      a2 = fmaf(w[j], h.z, a2);
      a3 = fmaf(w[j], h.w, a3);
    }
  }
  for (; e < e1; ++e) {
    int s = esrc[e];
    float w = ew[e];
    float4 h = *(const float4*)(Hc + (size_t)s * COLS);
    a0 = fmaf(w, h.x, a0);
    a1 = fmaf(w, h.y, a1);
    a2 = fmaf(w, h.z, a2);
    a3 = fmaf(w, h.w, a3);
  }

  float4 b = *(const float4*)(bias + c0);
  float4 o;
  o.x = fmaf(di, a0, b.x);
  o.y = fmaf(di, a1, b.y);
  o.z = fmaf(di, a2, b.z);
  o.w = fmaf(di, a3, b.w);
  *(float4*)(out + (size_t)node * COLS + c0) = o;
}

// ---------------- launch ----------------

extern "C" void kernel_launch(void* const* d_in, const int* in_sizes, int n_in,
                              void* d_out, int out_size, void* d_ws, size_t ws_size,
                              hipStream_t stream) {
  (void)n_in; (void)out_size; (void)ws_size;
  const float* x = (const float*)d_in[0];
  const int N = in_sizes[0] / 256;
  const int* ei = (const int*)d_in[1];
  const int E = in_sizes[1] / 2;
  const int* srcp = ei;
  const int* dstp = ei + E;
  const float* Wl6[6];
  const float* Bl[6];
  for (int i = 0; i < 6; i++) {
    Wl6[i] = (const float*)d_in[2 + 2 * i];
    Bl[i] = (const float*)d_in[3 + 2 * i];
  }
  float* out = (float*)d_out;

  char* p = (char*)d_ws;
  auto carve = [&](size_t bytes) {
    char* r = p;
    p += (bytes + 255) & ~(size_t)255;
    return (void*)r;
  };
  const int Mpad = (N + 255) & ~255;  // padded rows for clamped reads
  float* bufA = (float*)carve((size_t)N * 256 * 4);
  float* bufB = (float*)carve((size_t)N * 256 * 4);
  unsigned short* ah = (unsigned short*)carve((size_t)Mpad * 256 * 2);
  unsigned short* al = (unsigned short*)carve((size_t)Mpad * 256 * 2);
  unsigned short* wh = (unsigned short*)carve((size_t)256 * 256 * 2);
  unsigned short* wl = (unsigned short*)carve((size_t)256 * 256 * 2);
  int* cnt = (int*)carve((size_t)N * 4);
  float* dinv = (float*)carve((size_t)N * 4);
  int* incl = (int*)carve((size_t)N * 4);
  int* rowptr = (int*)carve((size_t)(N + 1) * 4);
  int* esrc = (int*)carve((size_t)E * 4);
  float* ew = (float*)carve((size_t)E * 4);
  int* bsum = (int*)carve(1024);
  int* boff = (int*)carve(1024);

  const int NB = (N + 255) / 256;

  hipMemsetAsync(cnt, 0, (size_t)N * 4, stream);
  hist_kernel<<<(E + 255) / 256, 256, 0, stream>>>(dstp, cnt, E);
  dinv_kernel<<<NB, 256, 0, stream>>>(cnt, dinv, N);
  scan1_kernel<<<NB, 256, 0, stream>>>(cnt, incl, bsum, N);
  scan2_kernel<<<1, 256, 0, stream>>>(bsum, boff, NB);
  scan3_kernel<<<NB, 256, 0, stream>>>(incl, boff, rowptr, N);
  hipMemsetAsync(cnt, 0, (size_t)N * 4, stream);
  scatter_kernel<<<(E + 255) / 256, 256, 0, stream>>>(srcp, dstp, rowptr, cnt, dinv,
                                                      esrc, ew, E);

  const int n4 = N * 64;            // float4 count for N x 256
  const int gsplit = (n4 + 255) / 256;
  const int gmfma_x = (N + 255) / 256;
  const int gagg256 = 8 * ((N + 31) / 32);
  const int gagg128 = 8 * ((N + 63) / 64);

  // layer 1: split x (no lrelu), split W1, mfma, aggregate
  split_kernel<false><<<gsplit, 256, 0, stream>>>(x, ah, al, n4);
  split_kernel<false><<<(256 * 64 + 255) / 256, 256, 0, stream>>>(Wl6[0], wh, wl, 256 * 64);
  mfma_gemm_kernel<256><<<dim3(gmfma_x, 4), 256, 0, stream>>>(ah, al, wh, wl, bufB, N);
  aggregate_kernel<256><<<gagg256, 256, 0, stream>>>(bufB, rowptr, esrc, ew, dinv, Bl[0], bufA, N);
  // layers 2..5
  for (int l = 1; l < 5; ++l) {
    split_kernel<true><<<gsplit, 256, 0, stream>>>(bufA, ah, al, n4);
    split_kernel<false><<<(256 * 64 + 255) / 256, 256, 0, stream>>>(Wl6[l], wh, wl, 256 * 64);
    mfma_gemm_kernel<256><<<dim3(gmfma_x, 4), 256, 0, stream>>>(ah, al, wh, wl, bufB, N);
    aggregate_kernel<256><<<gagg256, 256, 0, stream>>>(bufB, rowptr, esrc, ew, dinv, Bl[l], bufA, N);
  }
  // layer 6 (out dim 128)
  split_kernel<true><<<gsplit, 256, 0, stream>>>(bufA, ah, al, n4);
  split_kernel<false><<<(128 * 64 + 255) / 256, 256, 0, stream>>>(Wl6[5], wh, wl, 128 * 64);
  mfma_gemm_kernel<128><<<dim3(gmfma_x, 2), 256, 0, stream>>>(ah, al, wh, wl, bufB, N);
  aggregate_kernel<128><<<gagg128, 256, 0, stream>>>(bufB, rowptr, esrc, ew, dinv, Bl[5], out, N);
}

// Round 18
// 1105.076 us; speedup vs baseline: 1.4874x; 1.0474x over previous
//
#include <hip/hip_runtime.h>
#include <hip/hip_bf16.h>

#define K_DIM 256
__device__ __forceinline__ float lrelu_f(float x) { return x >= 0.f ? x : 0.2f * x; }

using bf16x8 = __attribute__((ext_vector_type(8))) short;
using f32x4 = __attribute__((ext_vector_type(4))) float;

__device__ __forceinline__ unsigned short f2bf(float x) {
  __hip_bfloat16 b = __float2bfloat16(x);
  return *(unsigned short*)&b;
}
__device__ __forceinline__ float bf2f(unsigned short u) {
  __hip_bfloat16 b = *(__hip_bfloat16*)&u;
  return __bfloat162float(b);
}

// ---------------- graph prep kernels ----------------

__global__ __launch_bounds__(256) void hist_kernel(const int* __restrict__ dst,
                                                   int* __restrict__ cnt, int E) {
  int e = blockIdx.x * 256 + threadIdx.x;
  if (e < E) atomicAdd(&cnt[dst[e]], 1);
}

__global__ __launch_bounds__(256) void dinv_kernel(const int* __restrict__ cnt,
                                                   float* __restrict__ dinv, int n) {
  int i = blockIdx.x * 256 + threadIdx.x;
  if (i < n) dinv[i] = rsqrtf((float)cnt[i] + 1.0f);
}

__global__ __launch_bounds__(256) void scan1_kernel(const int* __restrict__ cnt,
                                                    int* __restrict__ incl,
                                                    int* __restrict__ bsum, int n) {
  __shared__ int sm[256];
  int t = threadIdx.x;
  int i = blockIdx.x * 256 + t;
  int v = (i < n) ? cnt[i] : 0;
  sm[t] = v;
  __syncthreads();
  for (int off = 1; off < 256; off <<= 1) {
    int u = (t >= off) ? sm[t - off] : 0;
    __syncthreads();
    sm[t] += u;
    __syncthreads();
  }
  if (i < n) incl[i] = sm[t];
  if (t == 255) bsum[blockIdx.x] = sm[255];
}

__global__ __launch_bounds__(256) void scan2_kernel(const int* __restrict__ bsum,
                                                    int* __restrict__ boff, int nb) {
  __shared__ int sm[256];
  int t = threadIdx.x;
  int v = (t < nb) ? bsum[t] : 0;
  sm[t] = v;
  __syncthreads();
  for (int off = 1; off < 256; off <<= 1) {
    int u = (t >= off) ? sm[t - off] : 0;
    __syncthreads();
    sm[t] += u;
    __syncthreads();
  }
  boff[t] = sm[t] - v;  // exclusive
}

__global__ __launch_bounds__(256) void scan3_kernel(const int* __restrict__ incl,
                                                    const int* __restrict__ boff,
                                                    int* __restrict__ rowptr, int n) {
  int i = blockIdx.x * 256 + threadIdx.x;
  if (i < n) rowptr[i + 1] = incl[i] + boff[blockIdx.x];
  if (i == 0) rowptr[0] = 0;
}

__global__ __launch_bounds__(256) void scatter_kernel(const int* __restrict__ src,
                                                      const int* __restrict__ dst,
                                                      const int* __restrict__ rowptr,
                                                      int* __restrict__ cursor,
                                                      const float* __restrict__ dinv,
                                                      int* __restrict__ esrc,
                                                      float* __restrict__ ew, int E) {
  int e = blockIdx.x * 256 + threadIdx.x;
  if (e < E) {
    int d = dst[e];
    int p = rowptr[d] + atomicAdd(&cursor[d], 1);
    int s = src[e];
    esrc[p] = s;
    ew[p] = dinv[s];
  }
}

// ---------------- split: y=(lrelu)(in); hi=bf16(y); lo=bf16(y-hi) ----------------
// Used for layer-1 x and for weights; layers 2..6 activations are split inside
// the aggregate epilogue (R18 fusion).

template <bool LRELU>
__global__ __launch_bounds__(256) void split_kernel(const float* __restrict__ in,
                                                    unsigned short* __restrict__ hi,
                                                    unsigned short* __restrict__ lo,
                                                    int n4) {
  int i = blockIdx.x * 256 + threadIdx.x;
  if (i >= n4) return;
  float4 v = *(const float4*)(in + (size_t)i * 4);
  if (LRELU) {
    v.x = lrelu_f(v.x); v.y = lrelu_f(v.y); v.z = lrelu_f(v.z); v.w = lrelu_f(v.w);
  }
  ushort4 h, l;
  h.x = f2bf(v.x); l.x = f2bf(v.x - bf2f(h.x));
  h.y = f2bf(v.y); l.y = f2bf(v.y - bf2f(h.y));
  h.z = f2bf(v.z); l.z = f2bf(v.z - bf2f(h.z));
  h.w = f2bf(v.w); l.w = f2bf(v.w - bf2f(h.w));
  *(ushort4*)(hi + (size_t)i * 4) = h;
  *(ushort4*)(lo + (size_t)i * 4) = l;
}

// ---------------- MFMA GEMM: H[M,NCOLS] = (Ah+Al)[M,256] @ (Wh+Wl)[NCOLS,256]^T ----------------
// Split-bf16 3-term: Ah*Wh + Ah*Wl + Al*Wh (Al*Wl dropped, ~2^-18 rel; verified
// R17: absmax unchanged vs fp32 path).
// R18: 1D grid, N-tile index FASTEST (by = id % ny) so the ny blocks sharing an
// A-panel are dispatched concurrently across XCDs -> A fetched from HBM once,
// time-shared via L3 (R17: x-major grid re-read A 4x ~70us/dispatch).
// Block 256thr = 4 waves; block tile 256(M) x 64(N); wave tile 64x64.
// Same lane map for A and B frags -> k-permutation cancels in the dot product.
// C/D layout (m89-verified): col=lane&15, row=(lane>>4)*4+reg.

template <int NCOLS>
__global__ __launch_bounds__(256) void mfma_gemm_kernel(
    const unsigned short* __restrict__ Ah, const unsigned short* __restrict__ Al,
    const unsigned short* __restrict__ Wh, const unsigned short* __restrict__ Wl,
    float* __restrict__ H, int M) {
  constexpr int NY = NCOLS / 64;
  const int bx = blockIdx.x / NY;
  const int by = blockIdx.x % NY;
  const int tid = threadIdx.x;
  const int wv = tid >> 6;
  const int lane = tid & 63;
  const int r = lane & 15;
  const int g = lane >> 4;
  const int bm = bx * 256 + wv * 64;
  const int bn = by * 64;

  f32x4 acc[4][4];
#pragma unroll
  for (int i = 0; i < 4; ++i)
#pragma unroll
    for (int t = 0; t < 4; ++t) acc[i][t] = {0.f, 0.f, 0.f, 0.f};

  size_t aoff[4];
#pragma unroll
  for (int i = 0; i < 4; ++i) {
    int row = bm + i * 16 + r;
    if (row >= M) row = M - 1;
    aoff[i] = (size_t)row * K_DIM;
  }
  size_t woff[4];
#pragma unroll
  for (int t = 0; t < 4; ++t) woff[t] = (size_t)(bn + t * 16 + r) * K_DIM;

  for (int k0 = 0; k0 < K_DIM; k0 += 32) {
    const int kb = k0 + g * 8;
    bf16x8 ah[4], al[4], bh[4], bl[4];
#pragma unroll
    for (int i = 0; i < 4; ++i) {
      ah[i] = *(const bf16x8*)(Ah + aoff[i] + kb);
      al[i] = *(const bf16x8*)(Al + aoff[i] + kb);
    }
#pragma unroll
    for (int t = 0; t < 4; ++t) {
      bh[t] = *(const bf16x8*)(Wh + woff[t] + kb);
      bl[t] = *(const bf16x8*)(Wl + woff[t] + kb);
    }
#pragma unroll
    for (int i = 0; i < 4; ++i)
#pragma unroll
      for (int t = 0; t < 4; ++t) {
        acc[i][t] = __builtin_amdgcn_mfma_f32_16x16x32_bf16(ah[i], bh[t], acc[i][t], 0, 0, 0);
        acc[i][t] = __builtin_amdgcn_mfma_f32_16x16x32_bf16(ah[i], bl[t], acc[i][t], 0, 0, 0);
        acc[i][t] = __builtin_amdgcn_mfma_f32_16x16x32_bf16(al[i], bh[t], acc[i][t], 0, 0, 0);
      }
  }

#pragma unroll
  for (int i = 0; i < 4; ++i)
#pragma unroll
    for (int t = 0; t < 4; ++t) {
#pragma unroll
      for (int j = 0; j < 4; ++j) {
        int row = bm + i * 16 + g * 4 + j;
        if (row < M) H[(size_t)row * NCOLS + bn + t * 16 + r] = acc[i][t][j];
      }
    }
}

// ---------------- column-sliced aggregation, fused bias+lrelu+split epilogue ----------------
// out path (FUSE=false, layer 6): out[i] = dinv_i*agg + b  (fp32)
// fused path (FUSE=true, layers 1..5): ah/al = bf16split(lrelu(dinv_i*agg + b))
// CW=COLS/8 col-group per XCD (R7 win). LINEAR node order (R12: sort hurt).
// Simple 4-way edge batch (R13 8-deep was neutral; its VGPR=40 cut occ 71->55 in R17).

template <int COLS, bool FUSE>
__global__ __launch_bounds__(256) void aggregate_kernel(
    const float* __restrict__ H, const int* __restrict__ rowptr,
    const int* __restrict__ esrc, const float* __restrict__ ew,
    const float* __restrict__ dinv, const float* __restrict__ bias,
    float* __restrict__ out, unsigned short* __restrict__ oh,
    unsigned short* __restrict__ ol, int n) {
  constexpr int CW = COLS / 8;
  constexpr int TPN = CW / 4;
  constexpr int NPB = 256 / TPN;
  const int g = blockIdx.x & 7;
  const int nb = blockIdx.x >> 3;
  const int t = threadIdx.x;
  const int ln = t / TPN;
  const int ct = t % TPN;
  const int node = nb * NPB + ln;
  if (node >= n) return;
  const int c0 = g * CW + ct * 4;
  const float* __restrict__ Hc = H + c0;
  const float di = dinv[node];

  float4 hs = *(const float4*)(Hc + (size_t)node * COLS);
  float a0 = di * hs.x, a1 = di * hs.y, a2 = di * hs.z, a3 = di * hs.w;

  const int e1 = rowptr[node + 1];
  int e = rowptr[node];
  for (; e + 4 <= e1; e += 4) {
    int s0 = esrc[e + 0], s1 = esrc[e + 1], s2 = esrc[e + 2], s3 = esrc[e + 3];
    float w0 = ew[e + 0], w1 = ew[e + 1], w2 = ew[e + 2], w3 = ew[e + 3];
    float4 h0 = *(const float4*)(Hc + (size_t)s0 * COLS);
    float4 h1 = *(const float4*)(Hc + (size_t)s1 * COLS);
    float4 h2 = *(const float4*)(Hc + (size_t)s2 * COLS);
    float4 h3 = *(const float4*)(Hc + (size_t)s3 * COLS);
    a0 = fmaf(w3, h3.x, fmaf(w2, h2.x, fmaf(w1, h1.x, fmaf(w0, h0.x, a0))));
    a1 = fmaf(w3, h3.y, fmaf(w2, h2.y, fmaf(w1, h1.y, fmaf(w0, h0.y, a1))));
    a2 = fmaf(w3, h3.z, fmaf(w2, h2.z, fmaf(w1, h1.z, fmaf(w0, h0.z, a2))));
    a3 = fmaf(w3, h3.w, fmaf(w2, h2.w, fmaf(w1, h1.w, fmaf(w0, h0.w, a3))));
  }
  for (; e < e1; ++e) {
    int s = esrc[e];
    float w = ew[e];
    float4 h = *(const float4*)(Hc + (size_t)s * COLS);
    a0 = fmaf(w, h.x, a0);
    a1 = fmaf(w, h.y, a1);
    a2 = fmaf(w, h.z, a2);
    a3 = fmaf(w, h.w, a3);
  }

  float4 b = *(const float4*)(bias + c0);
  float o0 = fmaf(di, a0, b.x);
  float o1 = fmaf(di, a1, b.y);
  float o2 = fmaf(di, a2, b.z);
  float o3 = fmaf(di, a3, b.w);

  if constexpr (FUSE) {
    o0 = lrelu_f(o0); o1 = lrelu_f(o1); o2 = lrelu_f(o2); o3 = lrelu_f(o3);
    ushort4 h, l;
    h.x = f2bf(o0); l.x = f2bf(o0 - bf2f(h.x));
    h.y = f2bf(o1); l.y = f2bf(o1 - bf2f(h.y));
    h.z = f2bf(o2); l.z = f2bf(o2 - bf2f(h.z));
    h.w = f2bf(o3); l.w = f2bf(o3 - bf2f(h.w));
    *(ushort4*)(oh + (size_t)node * COLS + c0) = h;
    *(ushort4*)(ol + (size_t)node * COLS + c0) = l;
  } else {
    float4 o;
    o.x = o0; o.y = o1; o.z = o2; o.w = o3;
    *(float4*)(out + (size_t)node * COLS + c0) = o;
  }
}

// ---------------- launch ----------------

extern "C" void kernel_launch(void* const* d_in, const int* in_sizes, int n_in,
                              void* d_out, int out_size, void* d_ws, size_t ws_size,
                              hipStream_t stream) {
  (void)n_in; (void)out_size; (void)ws_size;
  const float* x = (const float*)d_in[0];
  const int N = in_sizes[0] / 256;
  const int* ei = (const int*)d_in[1];
  const int E = in_sizes[1] / 2;
  const int* srcp = ei;
  const int* dstp = ei + E;
  const float* Wl6[6];
  const float* Bl[6];
  for (int i = 0; i < 6; i++) {
    Wl6[i] = (const float*)d_in[2 + 2 * i];
    Bl[i] = (const float*)d_in[3 + 2 * i];
  }
  float* out = (float*)d_out;

  char* p = (char*)d_ws;
  auto carve = [&](size_t bytes) {
    char* r = p;
    p += (bytes + 255) & ~(size_t)255;
    return (void*)r;
  };
  const int Mpad = (N + 255) & ~255;  // padded rows for clamped frag reads
  float* bufB = (float*)carve((size_t)N * 256 * 4);
  unsigned short* ah = (unsigned short*)carve((size_t)Mpad * 256 * 2);
  unsigned short* al = (unsigned short*)carve((size_t)Mpad * 256 * 2);
  unsigned short* wh = (unsigned short*)carve((size_t)256 * 256 * 2);
  unsigned short* wl = (unsigned short*)carve((size_t)256 * 256 * 2);
  int* cnt = (int*)carve((size_t)N * 4);
  float* dinv = (float*)carve((size_t)N * 4);
  int* incl = (int*)carve((size_t)N * 4);
  int* rowptr = (int*)carve((size_t)(N + 1) * 4);
  int* esrc = (int*)carve((size_t)E * 4);
  float* ew = (float*)carve((size_t)E * 4);
  int* bsum = (int*)carve(1024);
  int* boff = (int*)carve(1024);

  const int NB = (N + 255) / 256;

  hipMemsetAsync(cnt, 0, (size_t)N * 4, stream);
  hist_kernel<<<(E + 255) / 256, 256, 0, stream>>>(dstp, cnt, E);
  dinv_kernel<<<NB, 256, 0, stream>>>(cnt, dinv, N);
  scan1_kernel<<<NB, 256, 0, stream>>>(cnt, incl, bsum, N);
  scan2_kernel<<<1, 256, 0, stream>>>(bsum, boff, NB);
  scan3_kernel<<<NB, 256, 0, stream>>>(incl, boff, rowptr, N);
  hipMemsetAsync(cnt, 0, (size_t)N * 4, stream);
  scatter_kernel<<<(E + 255) / 256, 256, 0, stream>>>(srcp, dstp, rowptr, cnt, dinv,
                                                      esrc, ew, E);

  const int n4 = N * 64;  // float4 count for N x 256
  const int gsplit = (n4 + 255) / 256;
  const int gmfma_x = (N + 255) / 256;
  const int gagg256 = 8 * ((N + 31) / 32);
  const int gagg128 = 8 * ((N + 63) / 64);

  // layer 1: split x (no lrelu), split W1, mfma, aggregate(fused split)
  split_kernel<false><<<gsplit, 256, 0, stream>>>(x, ah, al, n4);
  split_kernel<false><<<(256 * 64 + 255) / 256, 256, 0, stream>>>(Wl6[0], wh, wl, 256 * 64);
  mfma_gemm_kernel<256><<<gmfma_x * 4, 256, 0, stream>>>(ah, al, wh, wl, bufB, N);
  aggregate_kernel<256, true><<<gagg256, 256, 0, stream>>>(bufB, rowptr, esrc, ew, dinv,
                                                           Bl[0], nullptr, ah, al, N);
  // layers 2..5
  for (int l = 1; l < 5; ++l) {
    split_kernel<false><<<(256 * 64 + 255) / 256, 256, 0, stream>>>(Wl6[l], wh, wl, 256 * 64);
    mfma_gemm_kernel<256><<<gmfma_x * 4, 256, 0, stream>>>(ah, al, wh, wl, bufB, N);
    aggregate_kernel<256, true><<<gagg256, 256, 0, stream>>>(bufB, rowptr, esrc, ew, dinv,
                                                             Bl[l], nullptr, ah, al, N);
  }
  // layer 6 (out dim 128): aggregate writes fp32 d_out, no lrelu
  split_kernel<false><<<(128 * 64 + 255) / 256, 256, 0, stream>>>(Wl6[5], wh, wl, 128 * 64);
  mfma_gemm_kernel<128><<<gmfma_x * 2, 256, 0, stream>>>(ah, al, wh, wl, bufB, N);
  aggregate_kernel<128, false><<<gagg128, 256, 0, stream>>>(bufB, rowptr, esrc, ew, dinv,
                                                            Bl[5], out, nullptr, nullptr, N);
}

// Round 19
// 937.654 us; speedup vs baseline: 1.7530x; 1.1786x over previous
//
#include <hip/hip_runtime.h>
#include <hip/hip_bf16.h>

#define K_DIM 256
__device__ __forceinline__ float lrelu_f(float x) { return x >= 0.f ? x : 0.2f * x; }

using bf16x8 = __attribute__((ext_vector_type(8))) short;
using f32x4 = __attribute__((ext_vector_type(4))) float;

__device__ __forceinline__ unsigned short f2bf(float x) {
  __hip_bfloat16 b = __float2bfloat16(x);
  return *(unsigned short*)&b;
}
__device__ __forceinline__ float bf2f(unsigned short u) {
  __hip_bfloat16 b = *(__hip_bfloat16*)&u;
  return __bfloat162float(b);
}

// frag-major index: tile(row>>4, k>>5), lane=(row&15)+((k>>3)&3)*16, elem=k&7.
// Same permutation for A and W frags -> cancels in the MFMA dot product.
__device__ __forceinline__ size_t frag_idx(int row, int k) {
  return (((size_t)(row >> 4) * 8 + (k >> 5)) * 64 + (row & 15) + (((k >> 3) & 3) << 4)) * 8 +
         (k & 7);
}

// ---------------- graph prep kernels ----------------

__global__ __launch_bounds__(256) void hist_kernel(const int* __restrict__ dst,
                                                   int* __restrict__ cnt, int E) {
  int e = blockIdx.x * 256 + threadIdx.x;
  if (e < E) atomicAdd(&cnt[dst[e]], 1);
}

__global__ __launch_bounds__(256) void dinv_kernel(const int* __restrict__ cnt,
                                                   float* __restrict__ dinv, int n) {
  int i = blockIdx.x * 256 + threadIdx.x;
  if (i < n) dinv[i] = rsqrtf((float)cnt[i] + 1.0f);
}

__global__ __launch_bounds__(256) void scan1_kernel(const int* __restrict__ cnt,
                                                    int* __restrict__ incl,
                                                    int* __restrict__ bsum, int n) {
  __shared__ int sm[256];
  int t = threadIdx.x;
  int i = blockIdx.x * 256 + t;
  int v = (i < n) ? cnt[i] : 0;
  sm[t] = v;
  __syncthreads();
  for (int off = 1; off < 256; off <<= 1) {
    int u = (t >= off) ? sm[t - off] : 0;
    __syncthreads();
    sm[t] += u;
    __syncthreads();
  }
  if (i < n) incl[i] = sm[t];
  if (t == 255) bsum[blockIdx.x] = sm[255];
}

__global__ __launch_bounds__(256) void scan2_kernel(const int* __restrict__ bsum,
                                                    int* __restrict__ boff, int nb) {
  __shared__ int sm[256];
  int t = threadIdx.x;
  int v = (t < nb) ? bsum[t] : 0;
  sm[t] = v;
  __syncthreads();
  for (int off = 1; off < 256; off <<= 1) {
    int u = (t >= off) ? sm[t - off] : 0;
    __syncthreads();
    sm[t] += u;
    __syncthreads();
  }
  boff[t] = sm[t] - v;  // exclusive
}

__global__ __launch_bounds__(256) void scan3_kernel(const int* __restrict__ incl,
                                                    const int* __restrict__ boff,
                                                    int* __restrict__ rowptr, int n) {
  int i = blockIdx.x * 256 + threadIdx.x;
  if (i < n) rowptr[i + 1] = incl[i] + boff[blockIdx.x];
  if (i == 0) rowptr[0] = 0;
}

__global__ __launch_bounds__(256) void scatter_kernel(const int* __restrict__ src,
                                                      const int* __restrict__ dst,
                                                      const int* __restrict__ rowptr,
                                                      int* __restrict__ cursor,
                                                      const float* __restrict__ dinv,
                                                      int* __restrict__ esrc,
                                                      float* __restrict__ ew, int E) {
  int e = blockIdx.x * 256 + threadIdx.x;
  if (e < E) {
    int d = dst[e];
    int p = rowptr[d] + atomicAdd(&cursor[d], 1);
    int s = src[e];
    esrc[p] = s;
    ew[p] = dinv[s];
  }
}

__global__ __launch_bounds__(256) void zerotail_kernel(unsigned short* __restrict__ a,
                                                       unsigned short* __restrict__ b,
                                                       size_t start, size_t count) {
  size_t i = (size_t)blockIdx.x * 256 + threadIdx.x;
  if (i < count) {
    a[start + i] = 0;
    b[start + i] = 0;
  }
}

// ---------------- split: y=(lrelu)(in); hi/lo bf16 split, FRAG-MAJOR output ----------------

template <bool LRELU>
__global__ __launch_bounds__(256) void split_kernel(const float* __restrict__ in,
                                                    unsigned short* __restrict__ hi,
                                                    unsigned short* __restrict__ lo,
                                                    int n4) {
  int i = blockIdx.x * 256 + threadIdx.x;
  if (i >= n4) return;
  int flat = i * 4;
  int row = flat >> 8;
  int k = flat & 255;
  float4 v = *(const float4*)(in + (size_t)flat);
  if (LRELU) {
    v.x = lrelu_f(v.x); v.y = lrelu_f(v.y); v.z = lrelu_f(v.z); v.w = lrelu_f(v.w);
  }
  ushort4 h, l;
  h.x = f2bf(v.x); l.x = f2bf(v.x - bf2f(h.x));
  h.y = f2bf(v.y); l.y = f2bf(v.y - bf2f(h.y));
  h.z = f2bf(v.z); l.z = f2bf(v.z - bf2f(h.z));
  h.w = f2bf(v.w); l.w = f2bf(v.w - bf2f(h.w));
  size_t d = frag_idx(row, k);  // k%4==0, 4 elems stay within the 8-elem frag
  *(ushort4*)(hi + d) = h;
  *(ushort4*)(lo + d) = l;
}

// ---------------- MFMA GEMM: H[M,NCOLS] = (Ah+Al)[M,256] @ (Wh+Wl)[NCOLS,256]^T ----------------
// Split-bf16 3-term (R17-verified: absmax unchanged vs fp32 path).
// R19: operands stored FRAG-MAJOR -> every frag load is base + hwlane*16B, one
// contiguous 1KB burst (R18: row-major frag loads touched 16 scattered lines
// per instr -> TA/L2 request-issue bound, ~80us/dispatch vs ~8us compute floor).
// 1D grid, N-tile fastest (A panel L3-shared across its 4 consumer blocks).
// C/D layout (m89-verified): col=lane&15, row=(lane>>4)*4+reg.

template <int NCOLS>
__global__ __launch_bounds__(256) void mfma_gemm_kernel(
    const unsigned short* __restrict__ Ah, const unsigned short* __restrict__ Al,
    const unsigned short* __restrict__ Wh, const unsigned short* __restrict__ Wl,
    float* __restrict__ H, int M) {
  constexpr int NY = NCOLS / 64;
  const int bx = blockIdx.x / NY;
  const int by = blockIdx.x % NY;
  const int tid = threadIdx.x;
  const int wv = tid >> 6;
  const int lane = tid & 63;
  const int r = lane & 15;
  const int g = lane >> 4;
  const int bm = bx * 256 + wv * 64;
  const int bn = by * 64;

  f32x4 acc[4][4];
#pragma unroll
  for (int i = 0; i < 4; ++i)
#pragma unroll
    for (int t = 0; t < 4; ++t) acc[i][t] = {0.f, 0.f, 0.f, 0.f};

  // frag-major tile bases: tm = bm/16 + i, tn = bn/16 + t, tk = k0/32
  const int tm0 = bm >> 4;
  const int tn0 = bn >> 4;

  for (int tk = 0; tk < 8; ++tk) {
    bf16x8 ah[4], al[4], bh[4], bl[4];
#pragma unroll
    for (int i = 0; i < 4; ++i) {
      size_t base = (((size_t)(tm0 + i) * 8 + tk) * 64) * 8 + (size_t)lane * 8;
      ah[i] = *(const bf16x8*)(Ah + base);
      al[i] = *(const bf16x8*)(Al + base);
    }
#pragma unroll
    for (int t = 0; t < 4; ++t) {
      size_t base = (((size_t)(tn0 + t) * 8 + tk) * 64) * 8 + (size_t)lane * 8;
      bh[t] = *(const bf16x8*)(Wh + base);
      bl[t] = *(const bf16x8*)(Wl + base);
    }
#pragma unroll
    for (int i = 0; i < 4; ++i)
#pragma unroll
      for (int t = 0; t < 4; ++t) {
        acc[i][t] = __builtin_amdgcn_mfma_f32_16x16x32_bf16(ah[i], bh[t], acc[i][t], 0, 0, 0);
        acc[i][t] = __builtin_amdgcn_mfma_f32_16x16x32_bf16(ah[i], bl[t], acc[i][t], 0, 0, 0);
        acc[i][t] = __builtin_amdgcn_mfma_f32_16x16x32_bf16(al[i], bh[t], acc[i][t], 0, 0, 0);
      }
  }

#pragma unroll
  for (int i = 0; i < 4; ++i)
#pragma unroll
    for (int t = 0; t < 4; ++t) {
#pragma unroll
      for (int j = 0; j < 4; ++j) {
        int row = bm + i * 16 + g * 4 + j;
        if (row < M) H[(size_t)row * NCOLS + bn + t * 16 + r] = acc[i][t][j];
      }
    }
}

// ---------------- column-sliced aggregation, fused bias+lrelu+split epilogue ----------------
// out path (FUSE=false, layer 6): out[i] = dinv_i*agg + b  (fp32, row-major)
// fused path (FUSE=true): ah/al = bf16split(lrelu(dinv_i*agg + b)), FRAG-MAJOR.
// CW=COLS/8 col-group per XCD (R7 win). LINEAR node order (R12). Simple 4-way
// batch (R17: 8-deep's VGPR cost cut occupancy).

template <int COLS, bool FUSE>
__global__ __launch_bounds__(256) void aggregate_kernel(
    const float* __restrict__ H, const int* __restrict__ rowptr,
    const int* __restrict__ esrc, const float* __restrict__ ew,
    const float* __restrict__ dinv, const float* __restrict__ bias,
    float* __restrict__ out, unsigned short* __restrict__ oh,
    unsigned short* __restrict__ ol, int n) {
  constexpr int CW = COLS / 8;
  constexpr int TPN = CW / 4;
  constexpr int NPB = 256 / TPN;
  const int g = blockIdx.x & 7;
  const int nb = blockIdx.x >> 3;
  const int t = threadIdx.x;
  const int ln = t / TPN;
  const int ct = t % TPN;
  const int node = nb * NPB + ln;
  if (node >= n) return;
  const int c0 = g * CW + ct * 4;
  const float* __restrict__ Hc = H + c0;
  const float di = dinv[node];

  float4 hs = *(const float4*)(Hc + (size_t)node * COLS);
  float a0 = di * hs.x, a1 = di * hs.y, a2 = di * hs.z, a3 = di * hs.w;

  const int e1 = rowptr[node + 1];
  int e = rowptr[node];
  for (; e + 4 <= e1; e += 4) {
    int s0 = esrc[e + 0], s1 = esrc[e + 1], s2 = esrc[e + 2], s3 = esrc[e + 3];
    float w0 = ew[e + 0], w1 = ew[e + 1], w2 = ew[e + 2], w3 = ew[e + 3];
    float4 h0 = *(const float4*)(Hc + (size_t)s0 * COLS);
    float4 h1 = *(const float4*)(Hc + (size_t)s1 * COLS);
    float4 h2 = *(const float4*)(Hc + (size_t)s2 * COLS);
    float4 h3 = *(const float4*)(Hc + (size_t)s3 * COLS);
    a0 = fmaf(w3, h3.x, fmaf(w2, h2.x, fmaf(w1, h1.x, fmaf(w0, h0.x, a0))));
    a1 = fmaf(w3, h3.y, fmaf(w2, h2.y, fmaf(w1, h1.y, fmaf(w0, h0.y, a1))));
    a2 = fmaf(w3, h3.z, fmaf(w2, h2.z, fmaf(w1, h1.z, fmaf(w0, h0.z, a2))));
    a3 = fmaf(w3, h3.w, fmaf(w2, h2.w, fmaf(w1, h1.w, fmaf(w0, h0.w, a3))));
  }
  for (; e < e1; ++e) {
    int s = esrc[e];
    float w = ew[e];
    float4 h = *(const float4*)(Hc + (size_t)s * COLS);
    a0 = fmaf(w, h.x, a0);
    a1 = fmaf(w, h.y, a1);
    a2 = fmaf(w, h.z, a2);
    a3 = fmaf(w, h.w, a3);
  }

  float4 b = *(const float4*)(bias + c0);
  float o0 = fmaf(di, a0, b.x);
  float o1 = fmaf(di, a1, b.y);
  float o2 = fmaf(di, a2, b.z);
  float o3 = fmaf(di, a3, b.w);

  if constexpr (FUSE) {
    o0 = lrelu_f(o0); o1 = lrelu_f(o1); o2 = lrelu_f(o2); o3 = lrelu_f(o3);
    ushort4 h, l;
    h.x = f2bf(o0); l.x = f2bf(o0 - bf2f(h.x));
    h.y = f2bf(o1); l.y = f2bf(o1 - bf2f(h.y));
    h.z = f2bf(o2); l.z = f2bf(o2 - bf2f(h.z));
    h.w = f2bf(o3); l.w = f2bf(o3 - bf2f(h.w));
    size_t d = frag_idx(node, c0);
    *(ushort4*)(oh + d) = h;
    *(ushort4*)(ol + d) = l;
  } else {
    float4 o;
    o.x = o0; o.y = o1; o.z = o2; o.w = o3;
    *(float4*)(out + (size_t)node * COLS + c0) = o;
  }
}

// ---------------- launch ----------------

extern "C" void kernel_launch(void* const* d_in, const int* in_sizes, int n_in,
                              void* d_out, int out_size, void* d_ws, size_t ws_size,
                              hipStream_t stream) {
  (void)n_in; (void)out_size; (void)ws_size;
  const float* x = (const float*)d_in[0];
  const int N = in_sizes[0] / 256;
  const int* ei = (const int*)d_in[1];
  const int E = in_sizes[1] / 2;
  const int* srcp = ei;
  const int* dstp = ei + E;
  const float* Wl6[6];
  const float* Bl[6];
  for (int i = 0; i < 6; i++) {
    Wl6[i] = (const float*)d_in[2 + 2 * i];
    Bl[i] = (const float*)d_in[3 + 2 * i];
  }
  float* out = (float*)d_out;

  char* p = (char*)d_ws;
  auto carve = [&](size_t bytes) {
    char* r = p;
    p += (bytes + 255) & ~(size_t)255;
    return (void*)r;
  };
  const int Mpad = (N + 255) & ~255;
  float* bufB = (float*)carve((size_t)N * 256 * 4);
  unsigned short* ah = (unsigned short*)carve((size_t)Mpad * 256 * 2);
  unsigned short* al = (unsigned short*)carve((size_t)Mpad * 256 * 2);
  unsigned short* wh = (unsigned short*)carve((size_t)256 * 256 * 2);
  unsigned short* wl = (unsigned short*)carve((size_t)256 * 256 * 2);
  int* cnt = (int*)carve((size_t)N * 4);
  float* dinv = (float*)carve((size_t)N * 4);
  int* incl = (int*)carve((size_t)N * 4);
  int* rowptr = (int*)carve((size_t)(N + 1) * 4);
  int* esrc = (int*)carve((size_t)E * 4);
  float* ew = (float*)carve((size_t)E * 4);
  int* bsum = (int*)carve(1024);
  int* boff = (int*)carve(1024);

  const int NB = (N + 255) / 256;

  hipMemsetAsync(cnt, 0, (size_t)N * 4, stream);
  hist_kernel<<<(E + 255) / 256, 256, 0, stream>>>(dstp, cnt, E);
  dinv_kernel<<<NB, 256, 0, stream>>>(cnt, dinv, N);
  scan1_kernel<<<NB, 256, 0, stream>>>(cnt, incl, bsum, N);
  scan2_kernel<<<1, 256, 0, stream>>>(bsum, boff, NB);
  scan3_kernel<<<NB, 256, 0, stream>>>(incl, boff, rowptr, N);
  hipMemsetAsync(cnt, 0, (size_t)N * 4, stream);
  scatter_kernel<<<(E + 255) / 256, 256, 0, stream>>>(srcp, dstp, rowptr, cnt, dinv,
                                                      esrc, ew, E);
  // zero pad-tile frags (rows N..Mpad): MFMA reads them; zeros contribute 0.
  {
    size_t start = (size_t)(N / 16) * 8 * 64 * 8;
    size_t total = (size_t)(Mpad / 16) * 8 * 64 * 8;
    size_t count = total - start;
    zerotail_kernel<<<(int)((count + 255) / 256), 256, 0, stream>>>(ah, al, start, count);
  }

  const int n4 = N * 64;  // float4 count for N x 256
  const int gsplit = (n4 + 255) / 256;
  const int gmfma_x = Mpad / 256;
  const int gagg256 = 8 * ((N + 31) / 32);
  const int gagg128 = 8 * ((N + 63) / 64);

  // layer 1: split x (no lrelu) frag-major, split W1, mfma, aggregate(fused)
  split_kernel<false><<<gsplit, 256, 0, stream>>>(x, ah, al, n4);
  split_kernel<false><<<(256 * 64 + 255) / 256, 256, 0, stream>>>(Wl6[0], wh, wl, 256 * 64);
  mfma_gemm_kernel<256><<<gmfma_x * 4, 256, 0, stream>>>(ah, al, wh, wl, bufB, N);
  aggregate_kernel<256, true><<<gagg256, 256, 0, stream>>>(bufB, rowptr, esrc, ew, dinv,
                                                           Bl[0], nullptr, ah, al, N);
  // layers 2..5
  for (int l = 1; l < 5; ++l) {
    split_kernel<false><<<(256 * 64 + 255) / 256, 256, 0, stream>>>(Wl6[l], wh, wl, 256 * 64);
    mfma_gemm_kernel<256><<<gmfma_x * 4, 256, 0, stream>>>(ah, al, wh, wl, bufB, N);
    aggregate_kernel<256, true><<<gagg256, 256, 0, stream>>>(bufB, rowptr, esrc, ew, dinv,
                                                             Bl[l], nullptr, ah, al, N);
  }
  // layer 6 (out dim 128): aggregate writes fp32 d_out, no lrelu
  split_kernel<false><<<(128 * 64 + 255) / 256, 256, 0, stream>>>(Wl6[5], wh, wl, 128 * 64);
  mfma_gemm_kernel<128><<<gmfma_x * 2, 256, 0, stream>>>(ah, al, wh, wl, bufB, N);
  aggregate_kernel<128, false><<<gagg128, 256, 0, stream>>>(bufB, rowptr, esrc, ew, dinv,
                                                            Bl[5], out, nullptr, nullptr, N);
}

// Round 20
// 893.600 us; speedup vs baseline: 1.8394x; 1.0493x over previous
//
#include <hip/hip_runtime.h>
#include <hip/hip_bf16.h>

#define K_DIM 256
__device__ __forceinline__ float lrelu_f(float x) { return x >= 0.f ? x : 0.2f * x; }

using bf16x8 = __attribute__((ext_vector_type(8))) short;
using f32x4 = __attribute__((ext_vector_type(4))) float;

__device__ __forceinline__ unsigned short f2bf(float x) {
  __hip_bfloat16 b = __float2bfloat16(x);
  return *(unsigned short*)&b;
}
__device__ __forceinline__ float bf2f(unsigned short u) {
  __hip_bfloat16 b = *(__hip_bfloat16*)&u;
  return __bfloat162float(b);
}

// frag-major index: tile(row>>4, k>>5), lane=(row&15)+((k>>3)&3)*16, elem=k&7.
// Same permutation for A and W frags -> cancels in the MFMA dot product.
__device__ __forceinline__ size_t frag_idx(int row, int k) {
  return (((size_t)(row >> 4) * 8 + (k >> 5)) * 64 + (row & 15) + (((k >> 3) & 3) << 4)) * 8 +
         (k & 7);
}

// ---------------- graph prep kernels ----------------

__global__ __launch_bounds__(256) void hist_kernel(const int* __restrict__ dst,
                                                   int* __restrict__ cnt, int E) {
  int e = blockIdx.x * 256 + threadIdx.x;
  if (e < E) atomicAdd(&cnt[dst[e]], 1);
}

__global__ __launch_bounds__(256) void dinv_kernel(const int* __restrict__ cnt,
                                                   float* __restrict__ dinv, int n) {
  int i = blockIdx.x * 256 + threadIdx.x;
  if (i < n) dinv[i] = rsqrtf((float)cnt[i] + 1.0f);
}

__global__ __launch_bounds__(256) void scan1_kernel(const int* __restrict__ cnt,
                                                    int* __restrict__ incl,
                                                    int* __restrict__ bsum, int n) {
  __shared__ int sm[256];
  int t = threadIdx.x;
  int i = blockIdx.x * 256 + t;
  int v = (i < n) ? cnt[i] : 0;
  sm[t] = v;
  __syncthreads();
  for (int off = 1; off < 256; off <<= 1) {
    int u = (t >= off) ? sm[t - off] : 0;
    __syncthreads();
    sm[t] += u;
    __syncthreads();
  }
  if (i < n) incl[i] = sm[t];
  if (t == 255) bsum[blockIdx.x] = sm[255];
}

__global__ __launch_bounds__(256) void scan2_kernel(const int* __restrict__ bsum,
                                                    int* __restrict__ boff, int nb) {
  __shared__ int sm[256];
  int t = threadIdx.x;
  int v = (t < nb) ? bsum[t] : 0;
  sm[t] = v;
  __syncthreads();
  for (int off = 1; off < 256; off <<= 1) {
    int u = (t >= off) ? sm[t - off] : 0;
    __syncthreads();
    sm[t] += u;
    __syncthreads();
  }
  boff[t] = sm[t] - v;  // exclusive
}

__global__ __launch_bounds__(256) void scan3_kernel(const int* __restrict__ incl,
                                                    const int* __restrict__ boff,
                                                    int* __restrict__ rowptr, int n) {
  int i = blockIdx.x * 256 + threadIdx.x;
  if (i < n) rowptr[i + 1] = incl[i] + boff[blockIdx.x];
  if (i == 0) rowptr[0] = 0;
}

__global__ __launch_bounds__(256) void scatter_kernel(const int* __restrict__ src,
                                                      const int* __restrict__ dst,
                                                      const int* __restrict__ rowptr,
                                                      int* __restrict__ cursor,
                                                      const float* __restrict__ dinv,
                                                      int* __restrict__ esrc,
                                                      float* __restrict__ ew, int E) {
  int e = blockIdx.x * 256 + threadIdx.x;
  if (e < E) {
    int d = dst[e];
    int p = rowptr[d] + atomicAdd(&cursor[d], 1);
    int s = src[e];
    esrc[p] = s;
    ew[p] = dinv[s];
  }
}

__global__ __launch_bounds__(256) void zerotail_kernel(unsigned short* __restrict__ a,
                                                       unsigned short* __restrict__ b,
                                                       size_t start, size_t count) {
  size_t i = (size_t)blockIdx.x * 256 + threadIdx.x;
  if (i < count) {
    a[start + i] = 0;
    b[start + i] = 0;
  }
}

// ---------------- split: y=(lrelu)(in); hi/lo bf16 split, FRAG-MAJOR output ----------------

template <bool LRELU>
__global__ __launch_bounds__(256) void split_kernel(const float* __restrict__ in,
                                                    unsigned short* __restrict__ hi,
                                                    unsigned short* __restrict__ lo,
                                                    int n4) {
  int i = blockIdx.x * 256 + threadIdx.x;
  if (i >= n4) return;
  int flat = i * 4;
  int row = flat >> 8;
  int k = flat & 255;
  float4 v = *(const float4*)(in + (size_t)flat);
  if (LRELU) {
    v.x = lrelu_f(v.x); v.y = lrelu_f(v.y); v.z = lrelu_f(v.z); v.w = lrelu_f(v.w);
  }
  ushort4 h, l;
  h.x = f2bf(v.x); l.x = f2bf(v.x - bf2f(h.x));
  h.y = f2bf(v.y); l.y = f2bf(v.y - bf2f(h.y));
  h.z = f2bf(v.z); l.z = f2bf(v.z - bf2f(h.z));
  h.w = f2bf(v.w); l.w = f2bf(v.w - bf2f(h.w));
  size_t d = frag_idx(row, k);  // k%4==0, 4 elems stay within the 8-elem frag
  *(ushort4*)(hi + d) = h;
  *(ushort4*)(lo + d) = l;
}

// ---------------- MFMA GEMM: H[M,NCOLS] = (Ah+Al)[M,256] @ (Wh+Wl)[NCOLS,256]^T ----------------
// Split-bf16 3-term (R17-verified: absmax unchanged vs fp32 path).
// Frag-major operands (R19 win: 80->53us). R20: 512-thread block, tile 256Mx128N,
// 8 waves (4M x 2N) -> unique line-touches per block A 512KB + W 256KB; grid
// halves vs R19 -> device line-misses 500->300MB (L1-miss service ~1 line/4cyc/CU
// is the measured ceiling for both this kernel and the aggregate).
// N-tile fastest in 1D grid (A panel L3-shared). C/D layout m89-verified.

template <int NCOLS>
__global__ __launch_bounds__(512) void mfma_gemm_kernel(
    const unsigned short* __restrict__ Ah, const unsigned short* __restrict__ Al,
    const unsigned short* __restrict__ Wh, const unsigned short* __restrict__ Wl,
    float* __restrict__ H, int M) {
  constexpr int NY = NCOLS / 128;
  const int bx = blockIdx.x / NY;
  const int by = blockIdx.x % NY;
  const int tid = threadIdx.x;
  const int wv = tid >> 6;        // 0..7
  const int mg = wv & 3;          // M group
  const int ng = wv >> 2;         // N group
  const int lane = tid & 63;
  const int r = lane & 15;
  const int g = lane >> 4;
  const int bm = bx * 256 + mg * 64;
  const int bn = by * 128 + ng * 64;

  f32x4 acc[4][4];
#pragma unroll
  for (int i = 0; i < 4; ++i)
#pragma unroll
    for (int t = 0; t < 4; ++t) acc[i][t] = {0.f, 0.f, 0.f, 0.f};

  const int tm0 = bm >> 4;
  const int tn0 = bn >> 4;

  for (int tk = 0; tk < 8; ++tk) {
    bf16x8 ah[4], al[4], bh[4], bl[4];
#pragma unroll
    for (int i = 0; i < 4; ++i) {
      size_t base = (((size_t)(tm0 + i) * 8 + tk) * 64) * 8 + (size_t)lane * 8;
      ah[i] = *(const bf16x8*)(Ah + base);
      al[i] = *(const bf16x8*)(Al + base);
    }
#pragma unroll
    for (int t = 0; t < 4; ++t) {
      size_t base = (((size_t)(tn0 + t) * 8 + tk) * 64) * 8 + (size_t)lane * 8;
      bh[t] = *(const bf16x8*)(Wh + base);
      bl[t] = *(const bf16x8*)(Wl + base);
    }
#pragma unroll
    for (int i = 0; i < 4; ++i)
#pragma unroll
      for (int t = 0; t < 4; ++t) {
        acc[i][t] = __builtin_amdgcn_mfma_f32_16x16x32_bf16(ah[i], bh[t], acc[i][t], 0, 0, 0);
        acc[i][t] = __builtin_amdgcn_mfma_f32_16x16x32_bf16(ah[i], bl[t], acc[i][t], 0, 0, 0);
        acc[i][t] = __builtin_amdgcn_mfma_f32_16x16x32_bf16(al[i], bh[t], acc[i][t], 0, 0, 0);
      }
  }

#pragma unroll
  for (int i = 0; i < 4; ++i)
#pragma unroll
    for (int t = 0; t < 4; ++t) {
#pragma unroll
      for (int j = 0; j < 4; ++j) {
        int row = bm + i * 16 + g * 4 + j;
        if (row < M) H[(size_t)row * NCOLS + bn + t * 16 + r] = acc[i][t][j];
      }
    }
}

// ---------------- column-sliced aggregation, fused bias+lrelu+split epilogue ----------------
// out path (FUSE=false, layer 6): out[i] = dinv_i*agg + b  (fp32, row-major)
// fused path (FUSE=true): ah/al = bf16split(lrelu(dinv_i*agg + b)), FRAG-MAJOR.
// CW=COLS/8 col-group per XCD (R7 win). LINEAR node order (R12). Simple 4-way
// batch (R17: 8-deep's VGPR cost cut occupancy). R19 model: at the line-service
// floor (800k edges x 1KB row = 819MB of unique line touches) - structural.

template <int COLS, bool FUSE>
__global__ __launch_bounds__(256) void aggregate_kernel(
    const float* __restrict__ H, const int* __restrict__ rowptr,
    const int* __restrict__ esrc, const float* __restrict__ ew,
    const float* __restrict__ dinv, const float* __restrict__ bias,
    float* __restrict__ out, unsigned short* __restrict__ oh,
    unsigned short* __restrict__ ol, int n) {
  constexpr int CW = COLS / 8;
  constexpr int TPN = CW / 4;
  constexpr int NPB = 256 / TPN;
  const int g = blockIdx.x & 7;
  const int nb = blockIdx.x >> 3;
  const int t = threadIdx.x;
  const int ln = t / TPN;
  const int ct = t % TPN;
  const int node = nb * NPB + ln;
  if (node >= n) return;
  const int c0 = g * CW + ct * 4;
  const float* __restrict__ Hc = H + c0;
  const float di = dinv[node];

  float4 hs = *(const float4*)(Hc + (size_t)node * COLS);
  float a0 = di * hs.x, a1 = di * hs.y, a2 = di * hs.z, a3 = di * hs.w;

  const int e1 = rowptr[node + 1];
  int e = rowptr[node];
  for (; e + 4 <= e1; e += 4) {
    int s0 = esrc[e + 0], s1 = esrc[e + 1], s2 = esrc[e + 2], s3 = esrc[e + 3];
    float w0 = ew[e + 0], w1 = ew[e + 1], w2 = ew[e + 2], w3 = ew[e + 3];
    float4 h0 = *(const float4*)(Hc + (size_t)s0 * COLS);
    float4 h1 = *(const float4*)(Hc + (size_t)s1 * COLS);
    float4 h2 = *(const float4*)(Hc + (size_t)s2 * COLS);
    float4 h3 = *(const float4*)(Hc + (size_t)s3 * COLS);
    a0 = fmaf(w3, h3.x, fmaf(w2, h2.x, fmaf(w1, h1.x, fmaf(w0, h0.x, a0))));
    a1 = fmaf(w3, h3.y, fmaf(w2, h2.y, fmaf(w1, h1.y, fmaf(w0, h0.y, a1))));
    a2 = fmaf(w3, h3.z, fmaf(w2, h2.z, fmaf(w1, h1.z, fmaf(w0, h0.z, a2))));
    a3 = fmaf(w3, h3.w, fmaf(w2, h2.w, fmaf(w1, h1.w, fmaf(w0, h0.w, a3))));
  }
  for (; e < e1; ++e) {
    int s = esrc[e];
    float w = ew[e];
    float4 h = *(const float4*)(Hc + (size_t)s * COLS);
    a0 = fmaf(w, h.x, a0);
    a1 = fmaf(w, h.y, a1);
    a2 = fmaf(w, h.z, a2);
    a3 = fmaf(w, h.w, a3);
  }

  float4 b = *(const float4*)(bias + c0);
  float o0 = fmaf(di, a0, b.x);
  float o1 = fmaf(di, a1, b.y);
  float o2 = fmaf(di, a2, b.z);
  float o3 = fmaf(di, a3, b.w);

  if constexpr (FUSE) {
    o0 = lrelu_f(o0); o1 = lrelu_f(o1); o2 = lrelu_f(o2); o3 = lrelu_f(o3);
    ushort4 h, l;
    h.x = f2bf(o0); l.x = f2bf(o0 - bf2f(h.x));
    h.y = f2bf(o1); l.y = f2bf(o1 - bf2f(h.y));
    h.z = f2bf(o2); l.z = f2bf(o2 - bf2f(h.z));
    h.w = f2bf(o3); l.w = f2bf(o3 - bf2f(h.w));
    size_t d = frag_idx(node, c0);
    *(ushort4*)(oh + d) = h;
    *(ushort4*)(ol + d) = l;
  } else {
    float4 o;
    o.x = o0; o.y = o1; o.z = o2; o.w = o3;
    *(float4*)(out + (size_t)node * COLS + c0) = o;
  }
}

// ---------------- launch ----------------

extern "C" void kernel_launch(void* const* d_in, const int* in_sizes, int n_in,
                              void* d_out, int out_size, void* d_ws, size_t ws_size,
                              hipStream_t stream) {
  (void)n_in; (void)out_size; (void)ws_size;
  const float* x = (const float*)d_in[0];
  const int N = in_sizes[0] / 256;
  const int* ei = (const int*)d_in[1];
  const int E = in_sizes[1] / 2;
  const int* srcp = ei;
  const int* dstp = ei + E;
  const float* Wl6[6];
  const float* Bl[6];
  for (int i = 0; i < 6; i++) {
    Wl6[i] = (const float*)d_in[2 + 2 * i];
    Bl[i] = (const float*)d_in[3 + 2 * i];
  }
  float* out = (float*)d_out;

  char* p = (char*)d_ws;
  auto carve = [&](size_t bytes) {
    char* r = p;
    p += (bytes + 255) & ~(size_t)255;
    return (void*)r;
  };
  const int Mpad = (N + 255) & ~255;
  float* bufB = (float*)carve((size_t)N * 256 * 4);
  unsigned short* ah = (unsigned short*)carve((size_t)Mpad * 256 * 2);
  unsigned short* al = (unsigned short*)carve((size_t)Mpad * 256 * 2);
  unsigned short* wh = (unsigned short*)carve((size_t)256 * 256 * 2);
  unsigned short* wl = (unsigned short*)carve((size_t)256 * 256 * 2);
  int* cnt = (int*)carve((size_t)N * 4);
  float* dinv = (float*)carve((size_t)N * 4);
  int* incl = (int*)carve((size_t)N * 4);
  int* rowptr = (int*)carve((size_t)(N + 1) * 4);
  int* esrc = (int*)carve((size_t)E * 4);
  float* ew = (float*)carve((size_t)E * 4);
  int* bsum = (int*)carve(1024);
  int* boff = (int*)carve(1024);

  const int NB = (N + 255) / 256;

  hipMemsetAsync(cnt, 0, (size_t)N * 4, stream);
  hist_kernel<<<(E + 255) / 256, 256, 0, stream>>>(dstp, cnt, E);
  dinv_kernel<<<NB, 256, 0, stream>>>(cnt, dinv, N);
  scan1_kernel<<<NB, 256, 0, stream>>>(cnt, incl, bsum, N);
  scan2_kernel<<<1, 256, 0, stream>>>(bsum, boff, NB);
  scan3_kernel<<<NB, 256, 0, stream>>>(incl, boff, rowptr, N);
  hipMemsetAsync(cnt, 0, (size_t)N * 4, stream);
  scatter_kernel<<<(E + 255) / 256, 256, 0, stream>>>(srcp, dstp, rowptr, cnt, dinv,
                                                      esrc, ew, E);
  // zero pad-tile frags (rows N..Mpad): MFMA reads them; zeros contribute 0.
  {
    size_t start = (size_t)(N / 16) * 8 * 64 * 8;
    size_t total = (size_t)(Mpad / 16) * 8 * 64 * 8;
    size_t count = total - start;
    zerotail_kernel<<<(int)((count + 255) / 256), 256, 0, stream>>>(ah, al, start, count);
  }

  const int n4 = N * 64;  // float4 count for N x 256
  const int gsplit = (n4 + 255) / 256;
  const int gmfma256 = (Mpad / 256) * 2;  // 256x128 tiles, N fastest
  const int gmfma128 = (Mpad / 256) * 1;
  const int gagg256 = 8 * ((N + 31) / 32);
  const int gagg128 = 8 * ((N + 63) / 64);

  // layer 1: split x (no lrelu) frag-major, split W1, mfma, aggregate(fused)
  split_kernel<false><<<gsplit, 256, 0, stream>>>(x, ah, al, n4);
  split_kernel<false><<<(256 * 64 + 255) / 256, 256, 0, stream>>>(Wl6[0], wh, wl, 256 * 64);
  mfma_gemm_kernel<256><<<gmfma256, 512, 0, stream>>>(ah, al, wh, wl, bufB, N);
  aggregate_kernel<256, true><<<gagg256, 256, 0, stream>>>(bufB, rowptr, esrc, ew, dinv,
                                                           Bl[0], nullptr, ah, al, N);
  // layers 2..5
  for (int l = 1; l < 5; ++l) {
    split_kernel<false><<<(256 * 64 + 255) / 256, 256, 0, stream>>>(Wl6[l], wh, wl, 256 * 64);
    mfma_gemm_kernel<256><<<gmfma256, 512, 0, stream>>>(ah, al, wh, wl, bufB, N);
    aggregate_kernel<256, true><<<gagg256, 256, 0, stream>>>(bufB, rowptr, esrc, ew, dinv,
                                                             Bl[l], nullptr, ah, al, N);
  }
  // layer 6 (out dim 128): aggregate writes fp32 d_out, no lrelu
  split_kernel<false><<<(128 * 64 + 255) / 256, 256, 0, stream>>>(Wl6[5], wh, wl, 128 * 64);
  mfma_gemm_kernel<128><<<gmfma128, 512, 0, stream>>>(ah, al, wh, wl, bufB, N);
  aggregate_kernel<128, false><<<gagg128, 256, 0, stream>>>(bufB, rowptr, esrc, ew, dinv,
                                                            Bl[5], out, nullptr, nullptr, N);
}